// Round 1
// 205.629 us; speedup vs baseline: 1.2454x; 1.2454x over previous
//
#include <hip/hip_runtime.h>

typedef unsigned short u16;
typedef __bf16 bf16x8 __attribute__((ext_vector_type(8)));
typedef float   f32x4 __attribute__((ext_vector_type(4)));
typedef unsigned short u16x8 __attribute__((ext_vector_type(8)));

// ---------- helpers ----------
__device__ __forceinline__ u16 f2bf(float f) {
    unsigned int u = __builtin_bit_cast(unsigned int, f);
    u = u + 0x7FFFu + ((u >> 16) & 1u);   // round-to-nearest-even
    return (u16)(u >> 16);
}
__device__ __forceinline__ void gload16(const void* g, void* l) {
    __builtin_amdgcn_global_load_lds(
        (__attribute__((address_space(1))) void*)g,
        (__attribute__((address_space(3))) void*)l,
        16, 0, 0);
}

// ---------- kernel 1: fp32 -> bf16 cast (h) ----------
__global__ __launch_bounds__(256) void cvt_bf16(const float* __restrict__ x,
                                                u16* __restrict__ y, int n8) {
    int i = blockIdx.x * 256 + threadIdx.x;
    if (i >= n8) return;
    const f32x4* xp = (const f32x4*)x + (size_t)i * 2;
    f32x4 a = xp[0], b = xp[1];
    u16x8 o;
    o[0]=f2bf(a[0]); o[1]=f2bf(a[1]); o[2]=f2bf(a[2]); o[3]=f2bf(a[3]);
    o[4]=f2bf(b[0]); o[5]=f2bf(b[1]); o[6]=f2bf(b[2]); o[7]=f2bf(b[3]);
    ((u16x8*)y)[i] = o;
}

// ---------- kernel 2: Wq [K][N] fp32 -> WqT [N][K] bf16 ----------
__global__ __launch_bounds__(256) void transpose_cvt(const float* __restrict__ W,
                                                     u16* __restrict__ Wt) {
    __shared__ u16 tile[64][65];
    const int c0 = blockIdx.x * 64;
    const int r0 = blockIdx.y * 64;
    const int col = threadIdx.x & 63;
    const int rb  = (threadIdx.x >> 6) * 16;
    #pragma unroll
    for (int rr = 0; rr < 16; ++rr)
        tile[rb + rr][col] = f2bf(W[(size_t)(r0 + rb + rr) * 1024 + c0 + col]);
    __syncthreads();
    const int k = threadIdx.x & 63;
    #pragma unroll
    for (int rr = 0; rr < 16; ++rr) {
        int n = c0 + rb + rr;
        Wt[(size_t)n * 1024 + r0 + k] = tile[k][rb + rr];
    }
}

// ---------- kernel 3: W2T[b][j][h*64+d] = sum_e M0[b,h,d,e]*Wo[h*64+e][j] ----------
__global__ __launch_bounds__(256) void build_w2t(const float* __restrict__ M0,
                                                 const float* __restrict__ Wo,
                                                 u16* __restrict__ W2T) {
    const int jq = blockIdx.x, h = blockIdx.y, b = blockIdx.z;
    const int tid = threadIdx.x;
    const int j = jq * 256 + tid;
    __shared__ float m0s[64 * 64];
    const float* m0p = M0 + ((size_t)b * 16 + h) * 4096;
    for (int i = tid; i < 4096; i += 256) m0s[i] = m0p[i];
    __syncthreads();
    float wo[64];
    #pragma unroll
    for (int e = 0; e < 64; ++e) wo[e] = Wo[(size_t)(h * 64 + e) * 1024 + j];
    u16* outp = W2T + (size_t)b * 1024 * 1024 + (size_t)j * 1024 + h * 64;
    #pragma unroll 1
    for (int d = 0; d < 64; ++d) {
        float s = 0.f;
        #pragma unroll
        for (int e = 0; e < 64; ++e) s += m0s[d * 64 + e] * wo[e];
        outp[d] = f2bf(s);
    }
}

// ---------- GEMM: C[M,N] = A[M,K] * Bt[N,K]^T, bf16 in, fp32 acc ----------
// 256x256 tile, BK=64, 8 waves (2Mx4N, 128x64 per wave), 128 KiB dbuf LDS,
// 8-phase schedule (T3+T4 counted vmcnt), st-swizzle (T2), setprio (T5).
// LDS layout (bytes): A half-tiles [buf][half] at (buf*2+half)*16384,
// B at 65536 + same. Each half-tile = [128 rows][64 cols] bf16, row-major,
// with column-byte swizzle: byte ^= ((row&7)<<4). global_load_lds writes
// linearly, so the per-lane GLOBAL source column carries the inverse
// permutation ((lane&7)^(lane>>3))*8 (rule #21: both-sides-or-neither).
//
// Phase schedule per iteration (tiles T0=2i -> buf0, T1=2i+1 -> buf1):
//   P1: read A(qm0)+B(qn0) of T0; stage A0(T1)      | region free since prev P7
//   P2: read B(qn1) of T0;       stage A1(T1)
//   P3: read A(qm1) of T0;       stage B0(T2)->buf0 | buf0-B last read at P2
//   P4: (no reads)               stage B1(T2)->buf0 ; vmcnt(4)
//   P5-P8: same on buf1/T1; stages A0,A1(T2)->buf0, B0,B1(T3)->buf1; vmcnt(4) at P8
// vmcnt(4) = 2 half-tiles (4 loads/thread) in flight across the barrier.
template <int ACC_SSQ, int HAS_SCALE, typename CT>
__global__ __launch_bounds__(512, 2) void gemm256(const u16* __restrict__ A,
                                                  const u16* __restrict__ Bt,
                                                  CT* __restrict__ C,
                                                  float* __restrict__ ssq,
                                                  int M, int N, int K,
                                                  int bt_batch_stride, int rpb_log2) {
    __shared__ __align__(16) u16 lds[65536];   // 131072 B
    const int tid  = threadIdx.x;
    const int lane = tid & 63;
    const int w    = tid >> 6;       // 0..7
    const int wm   = w >> 2;         // 0..1  (two 128-row wave bands)
    const int wn   = w & 3;          // 0..3  (four 64-col wave bands)

    // XCD swizzle: 512 blocks = 128 mt x 4 nt; each XCD owns 16 consecutive
    // mt (A panel L2-resident, reused by its 4 nt blocks).
    const int id  = blockIdx.x;
    const int xcd = id & 7;
    const int loc = id >> 3;
    const int mt  = xcd * 16 + (loc >> 2);
    const int nt  = loc & 3;
    const int m0  = mt * 256;
    const int n0  = nt * 256;
    const u16* Btb = Bt + (size_t)(m0 >> rpb_log2) * (size_t)bt_batch_stride;

    // ---- staging addressing (per-lane global src carries inverse swizzle) ----
    const int l3 = lane >> 3;                    // row within 8-row group
    const int co = ((lane & 7) ^ l3) * 8;        // swizzled source column (elems)
    const u16* gA = A   + (size_t)(m0 + w * 16 + l3) * K + co;
    const u16* gB = Btb + (size_t)(n0 + w * 16 + l3) * K + co;
    char* const ldsb = (char*)lds;
    const int wdst = w * 2048;                   // wave-uniform LDS dest

    auto stA = [&](int buf, int h, int kt) {
        const u16* s = gA + (size_t)(h * 128) * K + kt * 64;
        char* d = ldsb + (buf * 2 + h) * 16384 + wdst;
        gload16(s, d);
        gload16(s + (size_t)8 * K, d + 1024);
    };
    auto stB = [&](int buf, int h, int kt) {
        const u16* s = gB + (size_t)(h * 128) * K + kt * 64;
        char* d = ldsb + 65536 + (buf * 2 + h) * 16384 + wdst;
        gload16(s, d);
        gload16(s + (size_t)8 * K, d + 1024);
    };

    // ---- fragment reads (swizzled ds_read_b128) ----
    const int rm   = lane & 15;
    const int kq   = (lane >> 4) * 16;           // k-chunk byte offset
    const int swzr = (rm & 7) << 4;
    auto ldA = [&](int buf, int qm, int m, int ks) -> bf16x8 {
        const int row = qm * 64 + m * 16 + rm;
        return *(const bf16x8*)(ldsb + (buf * 2 + wm) * 16384 + row * 128
                                + ((ks * 64 + kq) ^ swzr));
    };
    auto ldB = [&](int buf, int qn, int n, int ks) -> bf16x8 {
        const int row = (wn & 1) * 64 + qn * 32 + n * 16 + rm;
        return *(const bf16x8*)(ldsb + 65536 + (buf * 2 + (wn >> 1)) * 16384
                                + row * 128 + ((ks * 64 + kq) ^ swzr));
    };

    f32x4 acc[8][4] = {};
    bf16x8 a[8];       // current qm quadrant: [m][kstep]
    bf16x8 b[2][4];    // both qn quadrants:   [qn][n*2+kstep]

#define LOADA(buf, qm)                                                         \
    { _Pragma("unroll") for (int m_ = 0; m_ < 4; ++m_) {                       \
        _Pragma("unroll") for (int k_ = 0; k_ < 2; ++k_)                       \
            a[m_ * 2 + k_] = ldA(buf, qm, m_, k_); } }
#define LOADB(buf, qn)                                                         \
    { _Pragma("unroll") for (int n_ = 0; n_ < 2; ++n_) {                       \
        _Pragma("unroll") for (int k_ = 0; k_ < 2; ++k_)                       \
            b[qn][n_ * 2 + k_] = ldB(buf, qn, n_, k_); } }
#define MFMAQ(qm, qn)                                                          \
    { __builtin_amdgcn_s_setprio(1);                                           \
      _Pragma("unroll") for (int m_ = 0; m_ < 4; ++m_) {                       \
        _Pragma("unroll") for (int n_ = 0; n_ < 2; ++n_) {                     \
          _Pragma("unroll") for (int k_ = 0; k_ < 2; ++k_)                     \
            acc[(qm) * 4 + m_][(qn) * 2 + n_] =                                \
                __builtin_amdgcn_mfma_f32_16x16x32_bf16(                       \
                    a[m_ * 2 + k_], b[qn][n_ * 2 + k_],                        \
                    acc[(qm) * 4 + m_][(qn) * 2 + n_], 0, 0, 0); } }           \
      __builtin_amdgcn_s_setprio(0); }

    const int nkt = K >> 6;          // 16
    const int nit = nkt >> 1;        // 8

    // ---- prologue: tile0 (all 4 halves) + tile1 (B halves) = 12 loads ----
    stA(0, 0, 0); stA(0, 1, 0); stB(0, 0, 0); stB(0, 1, 0);
    stB(1, 0, 1); stB(1, 1, 1);
    asm volatile("s_waitcnt vmcnt(4)" ::: "memory");
    __builtin_amdgcn_s_barrier();

    #pragma unroll 1
    for (int i = 0; i < nit; ++i) {
        const int T1 = 2 * i + 1;
        int T2 = 2 * i + 2; if (T2 >= nkt) T2 -= nkt;   // wrap: waste-stage, uniform counts
        int T3 = 2 * i + 3; if (T3 >= nkt) T3 -= nkt;

        // P1
        LOADA(0, 0); LOADB(0, 0);
        stA(1, 0, T1);
        asm volatile("s_waitcnt lgkmcnt(8)" ::: "memory");
        __builtin_amdgcn_s_barrier();
        asm volatile("s_waitcnt lgkmcnt(0)" ::: "memory");
        MFMAQ(0, 0);
        __builtin_amdgcn_s_barrier();
        // P2
        LOADB(0, 1);
        stA(1, 1, T1);
        __builtin_amdgcn_s_barrier();
        asm volatile("s_waitcnt lgkmcnt(0)" ::: "memory");
        MFMAQ(0, 1);
        __builtin_amdgcn_s_barrier();
        // P3
        LOADA(0, 1);
        stB(0, 0, T2);
        __builtin_amdgcn_s_barrier();
        asm volatile("s_waitcnt lgkmcnt(0)" ::: "memory");
        MFMAQ(1, 0);
        __builtin_amdgcn_s_barrier();
        // P4
        stB(0, 1, T2);
        asm volatile("s_waitcnt vmcnt(4)" ::: "memory");
        __builtin_amdgcn_s_barrier();
        MFMAQ(1, 1);
        __builtin_amdgcn_s_barrier();
        // P5
        LOADA(1, 0); LOADB(1, 0);
        stA(0, 0, T2);
        asm volatile("s_waitcnt lgkmcnt(8)" ::: "memory");
        __builtin_amdgcn_s_barrier();
        asm volatile("s_waitcnt lgkmcnt(0)" ::: "memory");
        MFMAQ(0, 0);
        __builtin_amdgcn_s_barrier();
        // P6
        LOADB(1, 1);
        stA(0, 1, T2);
        __builtin_amdgcn_s_barrier();
        asm volatile("s_waitcnt lgkmcnt(0)" ::: "memory");
        MFMAQ(0, 1);
        __builtin_amdgcn_s_barrier();
        // P7
        LOADA(1, 1);
        stB(1, 0, T3);
        __builtin_amdgcn_s_barrier();
        asm volatile("s_waitcnt lgkmcnt(0)" ::: "memory");
        MFMAQ(1, 0);
        __builtin_amdgcn_s_barrier();
        // P8
        stB(1, 1, T3);
        asm volatile("s_waitcnt vmcnt(4)" ::: "memory");
        __builtin_amdgcn_s_barrier();
        MFMAQ(1, 1);
        __builtin_amdgcn_s_barrier();
    }
#undef LOADA
#undef LOADB
#undef MFMAQ

    // ---- epilogue ----  C layout: col=lane&15, row=(lane>>4)*4+reg [m89]
    asm volatile("s_waitcnt vmcnt(0)" ::: "memory");   // drain wrap-stages
    __syncthreads();
    float* lred = (float*)lds;     // 256 floats: row scales / row ssq
    if constexpr (HAS_SCALE) {
        if (tid < 256) {
            float q = ssq[m0 + tid];
            lred[tid] = 1.0f / fmaxf(sqrtf(q), 1e-12f);
        }
        __syncthreads();
    }
    if constexpr (ACC_SSQ) {
        if (tid < 256) lred[tid] = 0.f;
        __syncthreads();
    }
    const int cn = lane & 15;
    const int rq = (lane >> 4) * 4;
    #pragma unroll
    for (int m = 0; m < 8; ++m) {
        const int rbase = wm * 128 + m * 16 + rq;
        #pragma unroll
        for (int r = 0; r < 4; ++r) {
            const size_t rowoff = (size_t)(m0 + rbase + r) * N;
            float s = 0.f;
            #pragma unroll
            for (int n = 0; n < 4; ++n) {
                float x = acc[m][n][r];
                if constexpr (HAS_SCALE) x *= lred[rbase + r];
                if constexpr (ACC_SSQ) s += x * x;
                const int col = n0 + wn * 64 + n * 16 + cn;
                if constexpr (sizeof(CT) == 2) ((u16*)C)[rowoff + col] = f2bf(x);
                else                           C[rowoff + col] = x;
            }
            if constexpr (ACC_SSQ) {
                s += __shfl_xor(s, 1);
                s += __shfl_xor(s, 2);
                s += __shfl_xor(s, 4);
                s += __shfl_xor(s, 8);
                if (cn == 0) atomicAdd(&lred[rbase + r], s);  // 4 wn-waves share row
            }
        }
    }
    if constexpr (ACC_SSQ) {
        __syncthreads();
        if (tid < 256) atomicAdd(&ssq[m0 + tid], lred[tid]);  // 4 n-blocks per row
    }
}

// ---------- launch ----------
// B=4, S=8192, HID=PROJ=1024, NH=16, HD=64; M = B*S = 32768
// ws usage: 77.7 MiB. hbf lives in d_out's first half (dead after gemm1;
// gemm2 overwrites all of d_out — stream-ordered, safe).
extern "C" void kernel_launch(void* const* d_in, const int* in_sizes, int n_in,
                              void* d_out, int out_size, void* d_ws, size_t ws_size,
                              hipStream_t stream) {
    const float* h  = (const float*)d_in[0];   // [4,8192,1024]
    const float* Wq = (const float*)d_in[1];   // [1024,1024]
    const float* Wo = (const float*)d_in[7];   // [1024,1024]
    const float* M0 = (const float*)d_in[8];   // [4,16,64,64]
    float* out = (float*)d_out;

    char* ws = (char*)d_ws;
    u16*   hbf  = (u16*)d_out;                 // 67,108,864 B (first half of out)
    u16*   P    = (u16*)(ws);                  // 67,108,864 B
    u16*   WqT  = (u16*)(ws + 67108864);       //  2,097,152 B
    u16*   W2T  = (u16*)(ws + 69206016);       //  8,388,608 B
    float* ssq  = (float*)(ws + 77594624);     //    131,072 B  (end: 77,725,696)

    const int M = 32768, N = 1024, K = 1024;

    hipMemsetAsync(ssq, 0, M * sizeof(float), stream);   // graph-capture-safe
    cvt_bf16<<<16384, 256, 0, stream>>>(h, hbf, (M * K) / 8);
    transpose_cvt<<<dim3(16, 16), 256, 0, stream>>>(Wq, WqT);
    build_w2t<<<dim3(4, 16, 4), 256, 0, stream>>>(M0, Wo, W2T);
    // P = h @ Wq (bf16, un-normalized) + per-row ssq via atomics
    gemm256<1, 0, u16><<<512, 512, 0, stream>>>(
        hbf, WqT, P, ssq, M, N, K, 0, 0);
    // out = (1/max(sqrt(ssq),1e-12))[m] * (P @ W2T[batch]) ; batch = m >> 13
    gemm256<0, 1, float><<<512, 512, 0, stream>>>(
        P, W2T, out, ssq, M, N, K, 1024 * 1024, 13);
}